// Round 2
// baseline (4835.441 us; speedup 1.0000x reference)
//
#include <hip/hip_runtime.h>
#include <math.h>

#define N_PATHS 19
#define MUL 32
#define NB 4
#define CG_TOTAL 1225

// Path tables: order = reference loop order (l1 major, l2, l3 inner)
__constant__ int PL1[N_PATHS]  = {0,0,0,1,1,1,1,1,1,1,2,2,2,2,2,2,2,2,2};
__constant__ int PL2[N_PATHS]  = {0,1,2,0,1,1,1,2,2,2,0,1,1,1,2,2,2,2,2};
__constant__ int PL3[N_PATHS]  = {0,1,2,1,0,1,2,1,2,3,2,1,2,3,0,1,2,3,4};
// slot of each path within its l3 group (order of appearance)
__constant__ int PSLOT[N_PATHS]= {0,0,0,1,1,2,1,3,2,0,3,4,4,1,2,5,5,2,0};
// dense CG flat offsets (prefix over (2l1+1)(2l2+1)(2l3+1))
__constant__ int CGOFF[N_PATHS]= {0,1,10,35,44,53,80,125,170,245,350,375,420,495,600,625,700,825,1000};
__constant__ int FEATL[5] = {0, 96, 672, 1632, 2304};   // feat base per l3 group (k-major), total 2592
__constant__ int UPATH[5] = {96, 192, 192, 96, 32};     // mul_in per l3 group
__constant__ int IOFF[3]  = {0, 1, 4};                  // irrep offsets within the 9-dim input

__device__ float g_cg[CG_TOTAL];

// ---------------- CG setup (runs every launch; deterministic) ----------------
struct cplx { double re, im; };
__device__ inline cplx cmul(cplx a, cplx b){ return {a.re*b.re - a.im*b.im, a.re*b.im + a.im*b.re}; }

__device__ inline double dfact(int n){
  const double f[10] = {1.,1.,2.,6.,24.,120.,720.,5040.,40320.,362880.};
  return f[n];
}

__device__ double su2_cg(int j1,int j2,int j3,int m1,int m2){
  int m3 = m1+m2;
  if (j3 < abs(j1-j2) || j3 > j1+j2 || abs(m3) > j3) return 0.0;
  double pref = (2.0*j3+1.0)*dfact(j3+j1-j2)*dfact(j3-j1+j2)*dfact(j1+j2-j3)/dfact(j1+j2+j3+1);
  pref = sqrt(pref);
  pref *= sqrt(dfact(j3+m3)*dfact(j3-m3)*dfact(j1-m1)*dfact(j1+m1)*dfact(j2-m2)*dfact(j2+m2));
  double s = 0.0;
  for (int k=0; k<=j1+j2-j3; ++k){
    int a1=j1+j2-j3-k, a2=j1-m1-k, a3=j2+m2-k, a4=j3-j2+m1+k, a5=j3-j1-m2+k;
    if (a1<0||a2<0||a3<0||a4<0||a5<0) continue;
    double d = dfact(k)*dfact(a1)*dfact(a2)*dfact(a3)*dfact(a4)*dfact(a5);
    s += ((k&1)? -1.0:1.0)/d;
  }
  return pref*s;
}

// row r of q(l): at most 2 nonzeros. Returns count; cols/vals in out params.
__device__ int q_row(int l, int r, int* col, cplx* val){
  const double rt = 0.70710678118654752440;
  int m = r - l;
  int n;
  if (m < 0){
    col[0] = l - m; val[0] = {rt, 0.0};
    col[1] = l + m; val[1] = {0.0, -rt};
    n = 2;
  } else if (m == 0){
    col[0] = l; val[0] = {1.0, 0.0}; n = 1;
  } else {
    double s = (m & 1) ? -1.0 : 1.0;
    col[0] = l + m; val[0] = {s*rt, 0.0};
    col[1] = l - m; val[1] = {0.0, s*rt};
  n = 2;
  }
  // multiply by (-i)^l  (l=0:1, l=1:-i, l=2:-1, l=3:+i, l=4:1)
  #pragma unroll
  for (int t=0;t<2;t++){
    if (t >= n) break;
    cplx v = val[t];
    if (l == 1)      val[t] = { v.im, -v.re};   // *(-i)
    else if (l == 2) val[t] = {-v.re, -v.im};   // *(-1)
    else if (l == 3) val[t] = {-v.im,  v.re};   // *(+i)   <-- round-1 bug: was missing
    // l == 0, l == 4: *1
  }
  return n;
}

__global__ void setup_cg_kernel(){
  __shared__ double Tre[CG_TOTAL];
  __shared__ double Tim[CG_TOTAL];
  const int t = threadIdx.x;
  for (int idx = t; idx < CG_TOTAL; idx += blockDim.x){
    int p = N_PATHS-1;
    for (int q=0; q<N_PATHS-1; q++){ if (idx < CGOFF[q+1]) { p = q; break; } }
    int loc = idx - CGOFF[p];
    int l1 = PL1[p], l2 = PL2[p], l3 = PL3[p];
    int D2 = 2*l2+1, D3 = 2*l3+1;
    int a = loc / (D2*D3); int rem = loc - a*(D2*D3); int b = rem / D3; int c = rem - b*D3;
    int c1[2], c2[2], c3[2]; cplx v1[2], v2[2], v3[2];
    int n1 = q_row(l1, a, c1, v1);
    int n2 = q_row(l2, b, c2, v2);
    int n3 = q_row(l3, c, c3, v3);
    cplx acc = {0.0, 0.0};
    for (int t1=0; t1<n1; t1++){
      for (int t2=0; t2<n2; t2++){
        int m1 = c1[t1]-l1, m2 = c2[t2]-l2;
        int kk = l3 + m1 + m2;               // only nonzero k of C[i][j][:]
        if (kk < 0 || kk > 2*l3) continue;
        double cgv = su2_cg(l1,l2,l3,m1,m2);
        if (cgv == 0.0) continue;
        for (int t3=0; t3<n3; t3++){
          if (c3[t3] != kk) continue;
          cplx v3c = {v3[t3].re, -v3[t3].im}; // conj(q3)
          cplx prod = cmul(cmul(v1[t1], v2[t2]), v3c);
          acc.re += prod.re * cgv;
          acc.im += prod.im * cgv;
        }
      }
    }
    Tre[idx] = acc.re; Tim[idx] = acc.im;
  }
  __syncthreads();
  if (t < N_PATHS){
    int p = t;
    int l3 = PL3[p];
    int sz = (2*PL1[p]+1)*(2*PL2[p]+1)*(2*l3+1);
    int off = CGOFF[p];
    double sre = 0.0, sim = 0.0;
    for (int e=0; e<sz; e++){ sre += fabs(Tre[off+e]); sim += fabs(Tim[off+e]); }
    bool useRe = (sre >= sim);
    double norm = 1.0 / sqrt((double)(2*l3+1));
    for (int e=0; e<sz; e++){
      double v = useRe ? Tre[off+e] : Tim[off+e];
      g_cg[off+e] = (float)(v * norm);
    }
  }
}

// ---------------- main fused kernel (fp32) ----------------
// feat LDS layout is K-MAJOR per l3 group: feat[nl*2592 + FEATL[l3] + k*U_l + u']
// so phase-B can read float4 along u (16B-aligned since U_l % 4 == 0).
template<int L>
__device__ void phase_b(int o, const float* __restrict__ Wl, const float* feat,
                        float* __restrict__ out, int n0, int N){
  constexpr int K  = 2*L+1;
  constexpr int U  = (L==0?96 : L==1?192 : L==2?192 : L==3?96 : 32);
  constexpr int FB = (L==0?0  : L==1?96  : L==2?672 : L==3?1632 : 2304);
  constexpr int OB = (L==0?0  : L==1?64  : L==2?256 : L==3?576  : 800);
  const float scale = (L==0?0.1020620726f : L==1?0.0721687837f : L==2?0.0721687837f
                      : L==3?0.1020620726f : 0.1767766953f);   // 1/sqrt(U)
  float acc[NB][K];
  #pragma unroll
  for (int nl=0; nl<NB; nl++)
    #pragma unroll
    for (int k=0; k<K; k++) acc[nl][k] = 0.f;

  const float* __restrict__ wrow = Wl + o*U;
  for (int u=0; u<U; u+=4){
    const float4 w4 = *reinterpret_cast<const float4*>(&wrow[u]);
    #pragma unroll
    for (int nl=0; nl<NB; nl++){
      const float* fb = feat + nl*2592 + FB;
      #pragma unroll
      for (int k=0; k<K; k++){
        const float4 f4 = *reinterpret_cast<const float4*>(&fb[k*U + u]);
        acc[nl][k] += w4.x*f4.x + w4.y*f4.y + w4.z*f4.z + w4.w*f4.w;
      }
    }
  }
  #pragma unroll
  for (int nl=0; nl<NB; nl++){
    int n = n0 + nl;
    if (n < N){
      float* op = out + (size_t)n*944 + OB + o*K;
      #pragma unroll
      for (int k=0; k<K; k++) op[k] = acc[nl][k]*scale;
    }
  }
}

__global__ __launch_bounds__(256) void tp_main(
    const float* __restrict__ x1, const float* __restrict__ x2,
    const float* __restrict__ W0, const float* __restrict__ W1,
    const float* __restrict__ W2, const float* __restrict__ W3,
    const float* __restrict__ W4, float* __restrict__ out, int N)
{
  __shared__ __align__(16) float in1[NB*288];
  __shared__ __align__(16) float in2[NB*288];
  __shared__ __align__(16) float feat[NB*2592];
  const int t  = threadIdx.x;
  const int n0 = blockIdx.x * NB;

  // float4 staging of inputs (288 floats = 72 float4 per sample)
  const float4 z4 = {0.f,0.f,0.f,0.f};
  for (int idx = t; idx < NB*72; idx += 256){
    int nl = idx / 72, c4 = idx - nl*72;
    int n = n0 + nl;
    reinterpret_cast<float4*>(in1)[idx] =
        (n < N) ? reinterpret_cast<const float4*>(x1 + (size_t)n*288)[c4] : z4;
    reinterpret_cast<float4*>(in2)[idx] =
        (n < N) ? reinterpret_cast<const float4*>(x2 + (size_t)n*288)[c4] : z4;
  }
  __syncthreads();

  // phase A: feat[k-major] for all paths/muls/samples (dense CG from g_cg)
  for (int task = t; task < NB*N_PATHS*MUL; task += 256){
    int nl  = task / (N_PATHS*MUL);
    int rem = task - nl*(N_PATHS*MUL);
    int p   = rem / MUL;
    int m   = rem - p*MUL;
    int l1 = PL1[p], l2 = PL2[p], l3 = PL3[p];
    int D2 = 2*l2+1, K = 2*l3+1;
    int Ul = UPATH[l3];
    const float* cgp = g_cg + CGOFF[p];
    const float* s1 = &in1[nl*288 + m*9 + IOFF[l1]];
    const float* s2 = &in2[nl*288 + m*9 + IOFF[l2]];
    float acc[9];
    #pragma unroll
    for (int k=0;k<9;k++) acc[k]=0.f;
    for (int i=0; i<2*l1+1; i++){
      float av = s1[i];
      for (int j=0; j<D2; j++){
        float prod = av * s2[j];
        const float* ce = cgp + (i*D2 + j)*K;
        #pragma unroll
        for (int k=0;k<9;k++) if (k<K) acc[k] += ce[k]*prod;
      }
    }
    float* fd = &feat[nl*2592 + FEATL[l3] + PSLOT[p]*MUL + m];
    #pragma unroll
    for (int k=0;k<9;k++) if (k<K) fd[k*Ul] = acc[k];
  }
  __syncthreads();

  // phase B: per-(l,o) output rows; waves are l-uniform (w0:l0, w1:l1, w2:l2, w3:l3+l4)
  if (t < 64)        phase_b<0>(t,      W0, feat, out, n0, N);
  else if (t < 128)  phase_b<1>(t-64,   W1, feat, out, n0, N);
  else if (t < 192)  phase_b<2>(t-128,  W2, feat, out, n0, N);
  else if (t < 224)  phase_b<3>(t-192,  W3, feat, out, n0, N);
  else if (t < 240)  phase_b<4>(t-224,  W4, feat, out, n0, N);
}

extern "C" void kernel_launch(void* const* d_in, const int* in_sizes, int n_in,
                              void* d_out, int out_size, void* d_ws, size_t ws_size,
                              hipStream_t stream)
{
  (void)d_ws; (void)ws_size; (void)n_in; (void)out_size;
  const float* x1 = (const float*)d_in[0];
  const float* x2 = (const float*)d_in[1];
  const float* W0 = (const float*)d_in[2];
  const float* W1 = (const float*)d_in[3];
  const float* W2 = (const float*)d_in[4];
  const float* W3 = (const float*)d_in[5];
  const float* W4 = (const float*)d_in[6];
  float* out = (float*)d_out;
  int N = in_sizes[0] / 288;

  setup_cg_kernel<<<dim3(1), dim3(256), 0, stream>>>();
  int grid = (N + NB - 1) / NB;
  tp_main<<<dim3(grid), dim3(256), 0, stream>>>(x1, x2, W0, W1, W2, W3, W4, out, N);
}

// Round 3
// 655.667 us; speedup vs baseline: 7.3748x; 7.3748x over previous
//
#include <hip/hip_runtime.h>
#include <math.h>

typedef __attribute__((ext_vector_type(8))) short short8;
typedef __attribute__((ext_vector_type(4))) float f32x4;

#define N_PATHS 19
#define CG_TOTAL 1225
#define NSAMP 32            // samples per block
#define INSTRIDE 291        // padded LDS row stride (288+3; 291%32=3 -> ~2-way banks, free)

// ---- compile-time path tables (namespace scope, constexpr-indexable) ----
constexpr int kPL1[N_PATHS]  = {0,0,0,1,1,1,1,1,1,1,2,2,2,2,2,2,2,2,2};
constexpr int kPL2[N_PATHS]  = {0,1,2,0,1,1,1,2,2,2,0,1,1,1,2,2,2,2,2};
constexpr int kCGOFF[N_PATHS]= {0,1,10,35,44,53,80,125,170,245,350,375,420,495,600,625,700,825,1000};
constexpr int kIOFF[3]  = {0,1,4};
// slot -> path id, per l3 group (order of appearance in reference loop)
constexpr int kSP[5][6] = {{0,4,14,0,0,0},{1,3,5,7,11,15},{2,6,8,10,12,16},{9,13,17,0,0,0},{18,0,0,0,0,0}};
constexpr int kKS[5] = {3,6,6,3,1};     // K-steps (= path slots) per group
constexpr int kNT[5] = {4,4,4,2,1};     // N-tiles (O/16) per group
constexpr int kOB[5] = {0,64,256,576,800}; // output float offset per group
constexpr int kFB[5] = {0,12,36,60,66};    // W-fragment index base per group
#define N_FRAGS 67

// runtime M-tile worklist (wave-quarter -> list of (l,k) M-tiles), cost-balanced
__constant__ int cMT_L[25] = {1,1,1,0,4,4,4, 2,2,2,2, 2,3,3,3,3, 3,3,3,4,4,4,4,4,4};
__constant__ int cMT_K[25] = {0,1,2,0,6,7,8, 0,1,2,3, 4,0,1,2,3, 4,5,6,0,1,2,3,4,5};
__constant__ int cQO[5]    = {0,7,11,16,25};

__device__ float g_cg[CG_TOTAL];

__device__ inline unsigned short f2bf(float v){  // RNE fp32->bf16
  unsigned u = __builtin_bit_cast(unsigned, v);
  unsigned r = u + 0x7FFFu + ((u>>16)&1u);
  return (unsigned short)(r>>16);
}

// ---------------- CG setup (every launch; deterministic) ----------------
struct cplx { double re, im; };
__device__ inline cplx cmul(cplx a, cplx b){ return {a.re*b.re - a.im*b.im, a.re*b.im + a.im*b.re}; }
__device__ inline double dfact(int n){
  const double f[10] = {1.,1.,2.,6.,24.,120.,720.,5040.,40320.,362880.};
  return f[n];
}
__device__ double su2_cg(int j1,int j2,int j3,int m1,int m2){
  int m3 = m1+m2;
  if (j3 < abs(j1-j2) || j3 > j1+j2 || abs(m3) > j3) return 0.0;
  double pref = (2.0*j3+1.0)*dfact(j3+j1-j2)*dfact(j3-j1+j2)*dfact(j1+j2-j3)/dfact(j1+j2+j3+1);
  pref = sqrt(pref);
  pref *= sqrt(dfact(j3+m3)*dfact(j3-m3)*dfact(j1-m1)*dfact(j1+m1)*dfact(j2-m2)*dfact(j2+m2));
  double s = 0.0;
  for (int k=0; k<=j1+j2-j3; ++k){
    int a1=j1+j2-j3-k, a2=j1-m1-k, a3=j2+m2-k, a4=j3-j2+m1+k, a5=j3-j1-m2+k;
    if (a1<0||a2<0||a3<0||a4<0||a5<0) continue;
    double d = dfact(k)*dfact(a1)*dfact(a2)*dfact(a3)*dfact(a4)*dfact(a5);
    s += ((k&1)? -1.0:1.0)/d;
  }
  return pref*s;
}
__device__ int q_row(int l, int r, int* col, cplx* val){
  const double rt = 0.70710678118654752440;
  int m = r - l; int n;
  if (m < 0){ col[0]=l-m; val[0]={rt,0.0}; col[1]=l+m; val[1]={0.0,-rt}; n=2; }
  else if (m == 0){ col[0]=l; val[0]={1.0,0.0}; n=1; }
  else { double s=(m&1)?-1.0:1.0; col[0]=l+m; val[0]={s*rt,0.0}; col[1]=l-m; val[1]={0.0,s*rt}; n=2; }
  #pragma unroll
  for (int t=0;t<2;t++){
    if (t >= n) break;
    cplx v = val[t];
    if (l == 1)      val[t] = { v.im, -v.re};   // *(-i)
    else if (l == 2) val[t] = {-v.re, -v.im};   // *(-1)
    else if (l == 3) val[t] = {-v.im,  v.re};   // *(+i)
  }
  return n;
}
__constant__ int cPL1[N_PATHS]  = {0,0,0,1,1,1,1,1,1,1,2,2,2,2,2,2,2,2,2};
__constant__ int cPL2[N_PATHS]  = {0,1,2,0,1,1,1,2,2,2,0,1,1,1,2,2,2,2,2};
__constant__ int cPL3[N_PATHS]  = {0,1,2,1,0,1,2,1,2,3,2,1,2,3,0,1,2,3,4};
__constant__ int cCGOFF[N_PATHS]= {0,1,10,35,44,53,80,125,170,245,350,375,420,495,600,625,700,825,1000};

__global__ void setup_cg_kernel(){
  __shared__ double Tre[CG_TOTAL];
  __shared__ double Tim[CG_TOTAL];
  const int t = threadIdx.x;
  for (int idx = t; idx < CG_TOTAL; idx += blockDim.x){
    int p = N_PATHS-1;
    for (int q=0; q<N_PATHS-1; q++){ if (idx < cCGOFF[q+1]) { p = q; break; } }
    int loc = idx - cCGOFF[p];
    int l1 = cPL1[p], l2 = cPL2[p], l3 = cPL3[p];
    int D2 = 2*l2+1, D3 = 2*l3+1;
    int a = loc/(D2*D3); int rem = loc - a*(D2*D3); int b = rem/D3; int c = rem - b*D3;
    int c1[2], c2[2], c3[2]; cplx v1[2], v2[2], v3[2];
    int n1 = q_row(l1, a, c1, v1);
    int n2 = q_row(l2, b, c2, v2);
    int n3 = q_row(l3, c, c3, v3);
    cplx acc = {0.0, 0.0};
    for (int t1=0; t1<n1; t1++){
      for (int t2=0; t2<n2; t2++){
        int m1 = c1[t1]-l1, m2 = c2[t2]-l2;
        int kk = l3 + m1 + m2;
        if (kk < 0 || kk > 2*l3) continue;
        double cgv = su2_cg(l1,l2,l3,m1,m2);
        if (cgv == 0.0) continue;
        for (int t3=0; t3<n3; t3++){
          if (c3[t3] != kk) continue;
          cplx v3c = {v3[t3].re, -v3[t3].im};
          cplx prod = cmul(cmul(v1[t1], v2[t2]), v3c);
          acc.re += prod.re*cgv; acc.im += prod.im*cgv;
        }
      }
    }
    Tre[idx] = acc.re; Tim[idx] = acc.im;
  }
  __syncthreads();
  if (t < N_PATHS){
    int p = t, l3 = cPL3[p];
    int sz = (2*cPL1[p]+1)*(2*cPL2[p]+1)*(2*l3+1);
    int off = cCGOFF[p];
    double sre=0.0, sim=0.0;
    for (int e=0; e<sz; e++){ sre += fabs(Tre[off+e]); sim += fabs(Tim[off+e]); }
    bool useRe = (sre >= sim);
    double norm = 1.0/sqrt((double)(2*l3+1));
    for (int e=0; e<sz; e++){
      double v = useRe ? Tre[off+e] : Tim[off+e];
      g_cg[off+e] = (float)(v*norm);
    }
  }
}

// ---------------- W -> fragment-ordered bf16 (scale folded) ----------------
__global__ void prep_w_kernel(const float* __restrict__ W0, const float* __restrict__ W1,
                              const float* __restrict__ W2, const float* __restrict__ W3,
                              const float* __restrict__ W4, unsigned short* __restrict__ wout){
  int el = blockIdx.x*256 + threadIdx.x;
  if (el >= N_FRAGS*512) return;
  int frag = el>>9, r = el&511, lam = r>>3, j = r&7;
  int l  = (frag<12)?0 : (frag<36)?1 : (frag<60)?2 : (frag<66)?3 : 4;
  int fb = (l==0)?0 : (l==1)?12 : (l==2)?36 : (l==3)?60 : 66;
  int Ks = (l==0)?3 : (l==1)?6 : (l==2)?6 : (l==3)?3 : 1;
  int U  = (l==0)?96 : (l==1)?192 : (l==2)?192 : (l==3)?96 : 32;
  int rel = frag - fb, nt = rel/Ks, tt = rel - nt*Ks;
  int o = nt*16 + (lam&15);
  int u = tt*32 + (lam>>4)*8 + j;
  const float* W = (l==0)?W0 : (l==1)?W1 : (l==2)?W2 : (l==3)?W3 : W4;
  float scale = (l==0||l==3) ? 0.10206207261596575f
              : (l==4)       ? 0.17677669529663687f
                             : 0.07216878364870323f;
  wout[el] = f2bf(W[o*U + u] * scale);
}

// ---------------- main kernel ----------------
// A-frag element: lane(s=lane&15, g=lane>>4), j -> feat[sample s][u=tt*32+g*8+j][k]
template<int D1,int D2,int K>
__device__ inline short8 build_step(const float* i1p, const float* i2p, const float* cgs,
                                    int cgoff, int off1, int off2, int mb, int k){
  float cg[D1*D2];
  #pragma unroll
  for (int e=0; e<D1*D2; ++e) cg[e] = cgs[cgoff + e*K + k];
  short8 fr;
  #pragma unroll
  for (int j=0; j<8; ++j){
    const int m9 = (mb+j)*9;
    float av[D1];
    #pragma unroll
    for (int i=0; i<D1; ++i) av[i] = i1p[m9+off1+i];
    float acc = 0.f;
    #pragma unroll
    for (int jj=0; jj<D2; ++jj){
      float c = 0.f;
      #pragma unroll
      for (int i=0; i<D1; ++i) c = __builtin_fmaf(cg[i*D2+jj], av[i], c);
      acc = __builtin_fmaf(c, i2p[m9+off2+jj], acc);
    }
    fr[j] = (short)f2bf(acc);
  }
  return fr;
}

template<int L, int TT>
struct BuildAll {
  static __device__ inline void run(short8* af, int k, const float* i1p, const float* i2p,
                                    const float* cgs, int mb){
    constexpr int p  = kSP[L][TT];
    constexpr int l1 = kPL1[p], l2 = kPL2[p];
    af[TT] = build_step<2*l1+1, 2*l2+1, 2*L+1>(i1p, i2p, cgs, kCGOFF[p], kIOFF[l1], kIOFF[l2], mb, k);
    if constexpr (TT+1 < kKS[L]) BuildAll<L, TT+1>::run(af, k, i1p, i2p, cgs, mb);
  }
};

template<int L>
__device__ inline void process_mtile(int k, int lane, const float* i1p, const float* i2p,
                                     const float* cgs, const short* wfrag,
                                     float* __restrict__ out, int n0h, int N){
  constexpr int K = 2*L+1, Ks = kKS[L], Nt = kNT[L];
  const int g = lane>>4, mb = g*8;
  short8 af[Ks];
  BuildAll<L,0>::run(af, k, i1p, i2p, cgs, mb);
  const short* wf = wfrag + (size_t)kFB[L]*512;
  #pragma unroll
  for (int nt=0; nt<Nt; ++nt){
    f32x4 acc = {0.f,0.f,0.f,0.f};
    #pragma unroll
    for (int tt=0; tt<Ks; ++tt){
      const short8 bf = *reinterpret_cast<const short8*>(wf + (nt*Ks+tt)*512 + lane*8);
      acc = __builtin_amdgcn_mfma_f32_16x16x32_bf16(af[tt], bf, acc, 0, 0, 0);
    }
    const int obase = kOB[L] + (nt*16 + (lane&15))*K + k;
    #pragma unroll
    for (int r=0; r<4; ++r){
      int n = n0h + g*4 + r;       // D-frag row = sample (lane>>4)*4 + r  [m89 layout]
      if (n < N) out[(size_t)n*944 + obase] = acc[r];
    }
  }
}

__global__ __launch_bounds__(512, 4) void tp_main(
    const float* __restrict__ x1, const float* __restrict__ x2,
    const short* __restrict__ wfrag, float* __restrict__ out, int N)
{
  __shared__ float in1[NSAMP*INSTRIDE];
  __shared__ float in2[NSAMP*INSTRIDE];
  __shared__ float cgs[CG_TOTAL];
  const int t  = threadIdx.x;
  const int n0 = blockIdx.x * NSAMP;

  // stage inputs: float4 global loads, scalar LDS writes (stride 291)
  for (int q = t; q < NSAMP*72; q += 512){
    int row = q/72, c4 = q - row*72;
    int n = n0 + row;
    float4 v1 = {0,0,0,0}, v2 = {0,0,0,0};
    if (n < N){
      v1 = reinterpret_cast<const float4*>(x1 + (size_t)n*288)[c4];
      v2 = reinterpret_cast<const float4*>(x2 + (size_t)n*288)[c4];
    }
    int b = row*INSTRIDE + c4*4;
    in1[b+0]=v1.x; in1[b+1]=v1.y; in1[b+2]=v1.z; in1[b+3]=v1.w;
    in2[b+0]=v2.x; in2[b+1]=v2.y; in2[b+2]=v2.z; in2[b+3]=v2.w;
  }
  for (int q = t; q < CG_TOTAL; q += 512) cgs[q] = g_cg[q];
  __syncthreads();

  const int wave = t>>6, lane = t&63;
  const int h = wave>>2, q = wave&3;     // sample-half, M-tile quarter
  const int s = lane&15;
  const float* i1p = &in1[(h*16+s)*INSTRIDE];
  const float* i2p = &in2[(h*16+s)*INSTRIDE];
  const int n0h = n0 + h*16;

  const int qb = cQO[q], qe = cQO[q+1];
  for (int mi = qb; mi < qe; ++mi){
    int l = cMT_L[mi], k = cMT_K[mi];
    switch(l){
      case 0: process_mtile<0>(k, lane, i1p, i2p, cgs, wfrag, out, n0h, N); break;
      case 1: process_mtile<1>(k, lane, i1p, i2p, cgs, wfrag, out, n0h, N); break;
      case 2: process_mtile<2>(k, lane, i1p, i2p, cgs, wfrag, out, n0h, N); break;
      case 3: process_mtile<3>(k, lane, i1p, i2p, cgs, wfrag, out, n0h, N); break;
      case 4: process_mtile<4>(k, lane, i1p, i2p, cgs, wfrag, out, n0h, N); break;
    }
  }
}

extern "C" void kernel_launch(void* const* d_in, const int* in_sizes, int n_in,
                              void* d_out, int out_size, void* d_ws, size_t ws_size,
                              hipStream_t stream)
{
  (void)n_in; (void)out_size; (void)ws_size;
  const float* x1 = (const float*)d_in[0];
  const float* x2 = (const float*)d_in[1];
  const float* W0 = (const float*)d_in[2];
  const float* W1 = (const float*)d_in[3];
  const float* W2 = (const float*)d_in[4];
  const float* W3 = (const float*)d_in[5];
  const float* W4 = (const float*)d_in[6];
  float* out = (float*)d_out;
  int N = in_sizes[0] / 288;

  setup_cg_kernel<<<dim3(1), dim3(256), 0, stream>>>();
  prep_w_kernel<<<dim3((N_FRAGS*512 + 255)/256), dim3(256), 0, stream>>>(
      W0, W1, W2, W3, W4, (unsigned short*)d_ws);
  int grid = (N + NSAMP - 1) / NSAMP;
  tp_main<<<dim3(grid), dim3(512), 0, stream>>>(
      x1, x2, (const short*)d_ws, out, N);
}

// Round 4
// 400.228 us; speedup vs baseline: 12.0817x; 1.6382x over previous
//
#include <hip/hip_runtime.h>
#include <hip/hip_fp16.h>
#include <math.h>

typedef __attribute__((ext_vector_type(8))) short short8;
typedef __attribute__((ext_vector_type(4))) float f32x4;

#define N_PATHS 19
#define CG_TOTAL 1225
#define NSAMP 16
#define HSTRIDE 300        // __half stride per sample row (600B; 150 dw % 32 = 22 -> <=2-way)
#define SROW 321           // staging row stride in floats (<=2-way banks for all K)

// ---- compile-time path tables ----
constexpr int kPL1[N_PATHS]  = {0,0,0,1,1,1,1,1,1,1,2,2,2,2,2,2,2,2,2};
constexpr int kPL2[N_PATHS]  = {0,1,2,0,1,1,1,2,2,2,0,1,1,1,2,2,2,2,2};
constexpr int kCGOFF[N_PATHS]= {0,1,10,35,44,53,80,125,170,245,350,375,420,495,600,625,700,825,1000};
constexpr int kIOFF[3]  = {0,1,4};
constexpr int kSP[5][6] = {{0,4,14,0,0,0},{1,3,5,7,11,15},{2,6,8,10,12,16},{9,13,17,0,0,0},{18,0,0,0,0,0}};
constexpr int kKS[5] = {3,6,6,3,1};     // K-steps (path slots) per group
constexpr int kNT[5] = {4,4,4,2,1};     // N-tiles (O/16) per group
constexpr int kOB[5] = {0,64,256,576,800};
constexpr int kFB[5] = {0,12,36,60,66};
#define N_FRAGS 67

__device__ float g_cg[CG_TOTAL];

__device__ inline unsigned short f2bf(float v){  // RNE fp32->bf16
  unsigned u = __builtin_bit_cast(unsigned, v);
  unsigned r = u + 0x7FFFu + ((u>>16)&1u);
  return (unsigned short)(r>>16);
}

// ---------------- CG setup (every launch; deterministic) ----------------
struct cplx { double re, im; };
__device__ inline cplx cmul(cplx a, cplx b){ return {a.re*b.re - a.im*b.im, a.re*b.im + a.im*b.re}; }
__device__ inline double dfact(int n){
  const double f[10] = {1.,1.,2.,6.,24.,120.,720.,5040.,40320.,362880.};
  return f[n];
}
__device__ double su2_cg(int j1,int j2,int j3,int m1,int m2){
  int m3 = m1+m2;
  if (j3 < abs(j1-j2) || j3 > j1+j2 || abs(m3) > j3) return 0.0;
  double pref = (2.0*j3+1.0)*dfact(j3+j1-j2)*dfact(j3-j1+j2)*dfact(j1+j2-j3)/dfact(j1+j2+j3+1);
  pref = sqrt(pref);
  pref *= sqrt(dfact(j3+m3)*dfact(j3-m3)*dfact(j1-m1)*dfact(j1+m1)*dfact(j2-m2)*dfact(j2+m2));
  double s = 0.0;
  for (int k=0; k<=j1+j2-j3; ++k){
    int a1=j1+j2-j3-k, a2=j1-m1-k, a3=j2+m2-k, a4=j3-j2+m1+k, a5=j3-j1-m2+k;
    if (a1<0||a2<0||a3<0||a4<0||a5<0) continue;
    double d = dfact(k)*dfact(a1)*dfact(a2)*dfact(a3)*dfact(a4)*dfact(a5);
    s += ((k&1)? -1.0:1.0)/d;
  }
  return pref*s;
}
__device__ int q_row(int l, int r, int* col, cplx* val){
  const double rt = 0.70710678118654752440;
  int m = r - l; int n;
  if (m < 0){ col[0]=l-m; val[0]={rt,0.0}; col[1]=l+m; val[1]={0.0,-rt}; n=2; }
  else if (m == 0){ col[0]=l; val[0]={1.0,0.0}; n=1; }
  else { double s=(m&1)?-1.0:1.0; col[0]=l+m; val[0]={s*rt,0.0}; col[1]=l-m; val[1]={0.0,s*rt}; n=2; }
  #pragma unroll
  for (int t=0;t<2;t++){
    if (t >= n) break;
    cplx v = val[t];
    if (l == 1)      val[t] = { v.im, -v.re};   // *(-i)
    else if (l == 2) val[t] = {-v.re, -v.im};   // *(-1)
    else if (l == 3) val[t] = {-v.im,  v.re};   // *(+i)
  }
  return n;
}
__constant__ int cPL1[N_PATHS]  = {0,0,0,1,1,1,1,1,1,1,2,2,2,2,2,2,2,2,2};
__constant__ int cPL2[N_PATHS]  = {0,1,2,0,1,1,1,2,2,2,0,1,1,1,2,2,2,2,2};
__constant__ int cPL3[N_PATHS]  = {0,1,2,1,0,1,2,1,2,3,2,1,2,3,0,1,2,3,4};
__constant__ int cCGOFF[N_PATHS]= {0,1,10,35,44,53,80,125,170,245,350,375,420,495,600,625,700,825,1000};

__global__ void setup_cg_kernel(){
  __shared__ double Tre[CG_TOTAL];
  __shared__ double Tim[CG_TOTAL];
  const int t = threadIdx.x;
  for (int idx = t; idx < CG_TOTAL; idx += blockDim.x){
    int p = N_PATHS-1;
    for (int q=0; q<N_PATHS-1; q++){ if (idx < cCGOFF[q+1]) { p = q; break; } }
    int loc = idx - cCGOFF[p];
    int l1 = cPL1[p], l2 = cPL2[p], l3 = cPL3[p];
    int D2 = 2*l2+1, D3 = 2*l3+1;
    int a = loc/(D2*D3); int rem = loc - a*(D2*D3); int b = rem/D3; int c = rem - b*D3;
    int c1[2], c2[2], c3[2]; cplx v1[2], v2[2], v3[2];
    int n1 = q_row(l1, a, c1, v1);
    int n2 = q_row(l2, b, c2, v2);
    int n3 = q_row(l3, c, c3, v3);
    cplx acc = {0.0, 0.0};
    for (int t1=0; t1<n1; t1++){
      for (int t2=0; t2<n2; t2++){
        int m1 = c1[t1]-l1, m2 = c2[t2]-l2;
        int kk = l3 + m1 + m2;
        if (kk < 0 || kk > 2*l3) continue;
        double cgv = su2_cg(l1,l2,l3,m1,m2);
        if (cgv == 0.0) continue;
        for (int t3=0; t3<n3; t3++){
          if (c3[t3] != kk) continue;
          cplx v3c = {v3[t3].re, -v3[t3].im};
          cplx prod = cmul(cmul(v1[t1], v2[t2]), v3c);
          acc.re += prod.re*cgv; acc.im += prod.im*cgv;
        }
      }
    }
    Tre[idx] = acc.re; Tim[idx] = acc.im;
  }
  __syncthreads();
  if (t < N_PATHS){
    int p = t, l3 = cPL3[p];
    int sz = (2*cPL1[p]+1)*(2*cPL2[p]+1)*(2*l3+1);
    int off = cCGOFF[p];
    double sre=0.0, sim=0.0;
    for (int e=0; e<sz; e++){ sre += fabs(Tre[off+e]); sim += fabs(Tim[off+e]); }
    bool useRe = (sre >= sim);
    double norm = 1.0/sqrt((double)(2*l3+1));
    for (int e=0; e<sz; e++){
      double v = useRe ? Tre[off+e] : Tim[off+e];
      g_cg[off+e] = (float)(v*norm);
    }
  }
}

// ---------------- W -> fragment-ordered bf16 (scale folded) ----------------
__global__ void prep_w_kernel(const float* __restrict__ W0, const float* __restrict__ W1,
                              const float* __restrict__ W2, const float* __restrict__ W3,
                              const float* __restrict__ W4, unsigned short* __restrict__ wout){
  int el = blockIdx.x*256 + threadIdx.x;
  if (el >= N_FRAGS*512) return;
  int frag = el>>9, r = el&511, lam = r>>3, j = r&7;
  int l  = (frag<12)?0 : (frag<36)?1 : (frag<60)?2 : (frag<66)?3 : 4;
  int fb = (l==0)?0 : (l==1)?12 : (l==2)?36 : (l==3)?60 : 66;
  int Ks = (l==0)?3 : (l==1)?6 : (l==2)?6 : (l==3)?3 : 1;
  int U  = (l==0)?96 : (l==1)?192 : (l==2)?192 : (l==3)?96 : 32;
  int rel = frag - fb, nt = rel/Ks, tt = rel - nt*Ks;
  int o = nt*16 + (lam&15);
  int u = tt*32 + (lam>>4)*8 + j;
  const float* W = (l==0)?W0 : (l==1)?W1 : (l==2)?W2 : (l==3)?W3 : W4;
  float scale = (l==0||l==3) ? 0.10206207261596575f
              : (l==4)       ? 0.17677669529663687f
                             : 0.07216878364870323f;
  wout[el] = f2bf(W[o*U + u] * scale);
}

// ---------------- main kernel ----------------
template<int D1,int D2,int K>
__forceinline__ __device__ short8 build_step(const __half* i1p, const __half* i2p,
                                             int cgoff, int off1, int off2, int mb, int k){
  float cg[D1*D2];
  #pragma unroll
  for (int e=0; e<D1*D2; ++e) cg[e] = g_cg[cgoff + e*K + k];   // uniform addr -> s_load
  short8 fr;
  #pragma unroll
  for (int j=0; j<8; ++j){
    const int m9 = (mb+j)*9;
    float av[D1];
    #pragma unroll
    for (int i=0; i<D1; ++i) av[i] = __half2float(i1p[m9+off1+i]);
    float acc = 0.f;
    #pragma unroll
    for (int jj=0; jj<D2; ++jj){
      float c = 0.f;
      #pragma unroll
      for (int i=0; i<D1; ++i) c = __builtin_fmaf(cg[i*D2+jj], av[i], c);
      acc = __builtin_fmaf(c, __half2float(i2p[m9+off2+jj]), acc);
    }
    fr[j] = (short)f2bf(acc);
  }
  return fr;
}

template<int L, int TT>
struct BuildAll {
  static __forceinline__ __device__ void run(short8* af, int k, const __half* i1p,
                                             const __half* i2p, int mb){
    constexpr int p  = kSP[L][TT];
    constexpr int l1 = kPL1[p], l2 = kPL2[p];
    af[TT] = build_step<2*l1+1, 2*l2+1, 2*L+1>(i1p, i2p, kCGOFF[p], kIOFF[l1], kIOFF[l2], mb, k);
    if constexpr (TT+1 < kKS[L]) BuildAll<L, TT+1>::run(af, k, i1p, i2p, mb);
  }
};

template<int L>
__forceinline__ __device__ void do_item(int k, int ntb, int nte, int lane,
                                        const __half* i1p, const __half* i2p,
                                        const short* __restrict__ wfrag, float* stage){
  constexpr int K = 2*L+1, Ks = kKS[L];
  const int g = lane>>4, s = lane&15;
  short8 af[Ks];
  BuildAll<L,0>::run(af, k, i1p, i2p, g*8);
  const short* wf = wfrag + (size_t)kFB[L]*512;
  for (int nt=ntb; nt<nte; ++nt){
    f32x4 acc = {0.f,0.f,0.f,0.f};
    #pragma unroll
    for (int tt=0; tt<Ks; ++tt){
      const short8 bf = *reinterpret_cast<const short8*>(wf + (nt*Ks+tt)*512 + lane*8);
      acc = __builtin_amdgcn_mfma_f32_16x16x32_bf16(af[tt], bf, acc, 0, 0, 0);
    }
    #pragma unroll
    for (int r=0; r<4; ++r)
      stage[(g*4+r)*SROW + (nt*16+s)*K + k] = acc[r];   // D-frag row = sample g*4+r [m89]
  }
}

template<int L>
__forceinline__ __device__ void flush(const float* stage, float* __restrict__ out,
                                      int n0, int N, int t){
  constexpr int K = 2*L+1;
  constexpr int O = (L==3)?32 : (L==4)?16 : 64;
  constexpr int NF4 = O*K/4;           // 16,48,80,56,36
  constexpr int OB = kOB[L];
  for (int idx = t; idx < NSAMP*NF4; idx += 256){
    int smp = idx / NF4, c4 = idx - smp*NF4;
    const float* sp = stage + smp*SROW + c4*4;
    float4 v = {sp[0], sp[1], sp[2], sp[3]};
    int n = n0 + smp;
    if (n < N)
      *reinterpret_cast<float4*>(out + (size_t)n*944 + OB + c4*4) = v;
  }
}

__global__ __launch_bounds__(256, 4) void tp_main(
    const float* __restrict__ x1, const float* __restrict__ x2,
    const short* __restrict__ wfrag, float* __restrict__ out, int N)
{
  __shared__ __half in1[NSAMP*HSTRIDE];
  __shared__ __half in2[NSAMP*HSTRIDE];
  __shared__ float stage[NSAMP*SROW];
  const int t  = threadIdx.x;
  const int n0 = blockIdx.x * NSAMP;

  // stage inputs as fp16 (float4 global loads -> half4 LDS writes)
  for (int idx = t; idx < NSAMP*72; idx += 256){
    int row = idx/72, c4 = idx - row*72;
    int n = n0 + row;
    float4 v1 = {0,0,0,0}, v2 = {0,0,0,0};
    if (n < N){
      v1 = reinterpret_cast<const float4*>(x1 + (size_t)n*288)[c4];
      v2 = reinterpret_cast<const float4*>(x2 + (size_t)n*288)[c4];
    }
    int b = row*HSTRIDE + c4*4;
    ushort4 u1, u2;
    u1.x = __half_as_ushort(__float2half_rn(v1.x)); u1.y = __half_as_ushort(__float2half_rn(v1.y));
    u1.z = __half_as_ushort(__float2half_rn(v1.z)); u1.w = __half_as_ushort(__float2half_rn(v1.w));
    u2.x = __half_as_ushort(__float2half_rn(v2.x)); u2.y = __half_as_ushort(__float2half_rn(v2.y));
    u2.z = __half_as_ushort(__float2half_rn(v2.z)); u2.w = __half_as_ushort(__float2half_rn(v2.w));
    *reinterpret_cast<ushort4*>(&in1[b]) = u1;
    *reinterpret_cast<ushort4*>(&in2[b]) = u2;
  }
  __syncthreads();

  const int q    = __builtin_amdgcn_readfirstlane(t>>6);   // wave id (uniform)
  const int lane = t&63;
  const __half* i1p = &in1[(lane&15)*HSTRIDE];
  const __half* i2p = &in2[(lane&15)*HSTRIDE];

  // ---- group L=0 (K=1): nt split across waves (A-frags replicated) ----
  do_item<0>(0, q, q+1, lane, i1p, i2p, wfrag, stage);
  __syncthreads(); flush<0>(stage, out, n0, N, t); __syncthreads();

  // ---- group L=1 (K=3, Nt=4) ----
  if      (q==0) do_item<1>(0, 0, 4, lane, i1p, i2p, wfrag, stage);
  else if (q==1) do_item<1>(1, 0, 4, lane, i1p, i2p, wfrag, stage);
  else if (q==2) do_item<1>(2, 0, 2, lane, i1p, i2p, wfrag, stage);
  else           do_item<1>(2, 2, 4, lane, i1p, i2p, wfrag, stage);
  __syncthreads(); flush<1>(stage, out, n0, N, t); __syncthreads();

  // ---- group L=2 (K=5, Nt=4): each wave k=q full nt, plus k=4 nt=q ----
  do_item<2>(q, 0, 4, lane, i1p, i2p, wfrag, stage);
  do_item<2>(4, q, q+1, lane, i1p, i2p, wfrag, stage);
  __syncthreads(); flush<2>(stage, out, n0, N, t); __syncthreads();

  // ---- group L=3 (K=7, Nt=2) ----
  if (q < 3){
    do_item<3>(q,   0, 2, lane, i1p, i2p, wfrag, stage);
    do_item<3>(q+4, 0, 2, lane, i1p, i2p, wfrag, stage);
  } else {
    do_item<3>(3,   0, 2, lane, i1p, i2p, wfrag, stage);
  }
  __syncthreads(); flush<3>(stage, out, n0, N, t); __syncthreads();

  // ---- group L=4 (K=9, Nt=1) ----
  if (q < 3){
    do_item<4>(2*q,   0, 1, lane, i1p, i2p, wfrag, stage);
    do_item<4>(2*q+1, 0, 1, lane, i1p, i2p, wfrag, stage);
  } else {
    do_item<4>(6, 0, 1, lane, i1p, i2p, wfrag, stage);
    do_item<4>(7, 0, 1, lane, i1p, i2p, wfrag, stage);
    do_item<4>(8, 0, 1, lane, i1p, i2p, wfrag, stage);
  }
  __syncthreads(); flush<4>(stage, out, n0, N, t);
}

extern "C" void kernel_launch(void* const* d_in, const int* in_sizes, int n_in,
                              void* d_out, int out_size, void* d_ws, size_t ws_size,
                              hipStream_t stream)
{
  (void)n_in; (void)out_size; (void)ws_size;
  const float* x1 = (const float*)d_in[0];
  const float* x2 = (const float*)d_in[1];
  const float* W0 = (const float*)d_in[2];
  const float* W1 = (const float*)d_in[3];
  const float* W2 = (const float*)d_in[4];
  const float* W3 = (const float*)d_in[5];
  const float* W4 = (const float*)d_in[6];
  float* out = (float*)d_out;
  int N = in_sizes[0] / 288;

  setup_cg_kernel<<<dim3(1), dim3(256), 0, stream>>>();
  prep_w_kernel<<<dim3((N_FRAGS*512 + 255)/256), dim3(256), 0, stream>>>(
      W0, W1, W2, W3, W4, (unsigned short*)d_ws);
  int grid = (N + NSAMP - 1) / NSAMP;
  tp_main<<<dim3(grid), dim3(256), 0, stream>>>(
      x1, x2, (const short*)d_ws, out, N);
}

// Round 5
// 383.925 us; speedup vs baseline: 12.5948x; 1.0425x over previous
//
#include <hip/hip_runtime.h>
#include <math.h>

typedef __attribute__((ext_vector_type(8))) short short8;
typedef __attribute__((ext_vector_type(4))) float f32x4;
typedef __attribute__((ext_vector_type(4))) unsigned u32x4;

#define N_PATHS 19
#define CG_TOTAL 1225
#define SROW 148            // stage row stride (floats): >=144, %4==0, banks ~2-way

// ---- compile-time path tables ----
constexpr int kPL1[N_PATHS]  = {0,0,0,1,1,1,1,1,1,1,2,2,2,2,2,2,2,2,2};
constexpr int kPL2[N_PATHS]  = {0,1,2,0,1,1,1,2,2,2,0,1,1,1,2,2,2,2,2};
constexpr int kCGOFF[N_PATHS]= {0,1,10,35,44,53,80,125,170,245,350,375,420,495,600,625,700,825,1000};
constexpr int kIOFF[3]  = {0,1,4};
constexpr int kSP[5][6] = {{0,4,14,0,0,0},{1,3,5,7,11,15},{2,6,8,10,12,16},{9,13,17,0,0,0},{18,0,0,0,0,0}};
constexpr int kKS[5] = {3,6,6,3,1};
constexpr int kNT[5] = {4,4,4,2,1};
constexpr int kOB[5] = {0,64,256,576,800};
constexpr int kFB[5] = {0,12,36,60,66};
#define N_FRAGS 67

__device__ float g_cg[CG_TOTAL];

// superset of the real-basis Wigner nonzero pattern (necessary condition
// from q-matrix structure: each row of q has support only at m-cols ±|m|,
// and SU2 CG needs sigma1+sigma2=sigma3) -> |m3| in {|m1|+|m2|, ||m1|-|m2||}.
// Extra entries multiply true zeros from g_cg: correctness-safe.
constexpr bool nzp(int l1, int l2, int l3, int i, int jj, int k){
  int m1 = i - l1, m2 = jj - l2, m3 = k - l3;
  int a1 = m1 < 0 ? -m1 : m1, a2 = m2 < 0 ? -m2 : m2, a3 = m3 < 0 ? -m3 : m3;
  int s = a1 + a2, d = a1 - a2; if (d < 0) d = -d;
  return a3 == s || a3 == d;
}

__device__ inline unsigned short f2bf(float v){  // RNE fp32->bf16
  unsigned u = __builtin_bit_cast(unsigned, v);
  unsigned r = u + 0x7FFFu + ((u>>16)&1u);
  return (unsigned short)(r>>16);
}

// ---------------- CG setup (every launch; deterministic) ----------------
struct cplx { double re, im; };
__device__ inline cplx cmul(cplx a, cplx b){ return {a.re*b.re - a.im*b.im, a.re*b.im + a.im*b.re}; }
__device__ inline double dfact(int n){
  const double f[10] = {1.,1.,2.,6.,24.,120.,720.,5040.,40320.,362880.};
  return f[n];
}
__device__ double su2_cg(int j1,int j2,int j3,int m1,int m2){
  int m3 = m1+m2;
  if (j3 < abs(j1-j2) || j3 > j1+j2 || abs(m3) > j3) return 0.0;
  double pref = (2.0*j3+1.0)*dfact(j3+j1-j2)*dfact(j3-j1+j2)*dfact(j1+j2-j3)/dfact(j1+j2+j3+1);
  pref = sqrt(pref);
  pref *= sqrt(dfact(j3+m3)*dfact(j3-m3)*dfact(j1-m1)*dfact(j1+m1)*dfact(j2-m2)*dfact(j2+m2));
  double s = 0.0;
  for (int k=0; k<=j1+j2-j3; ++k){
    int a1=j1+j2-j3-k, a2=j1-m1-k, a3=j2+m2-k, a4=j3-j2+m1+k, a5=j3-j1-m2+k;
    if (a1<0||a2<0||a3<0||a4<0||a5<0) continue;
    double d = dfact(k)*dfact(a1)*dfact(a2)*dfact(a3)*dfact(a4)*dfact(a5);
    s += ((k&1)? -1.0:1.0)/d;
  }
  return pref*s;
}
__device__ int q_row(int l, int r, int* col, cplx* val){
  const double rt = 0.70710678118654752440;
  int m = r - l; int n;
  if (m < 0){ col[0]=l-m; val[0]={rt,0.0}; col[1]=l+m; val[1]={0.0,-rt}; n=2; }
  else if (m == 0){ col[0]=l; val[0]={1.0,0.0}; n=1; }
  else { double s=(m&1)?-1.0:1.0; col[0]=l+m; val[0]={s*rt,0.0}; col[1]=l-m; val[1]={0.0,s*rt}; n=2; }
  #pragma unroll
  for (int t=0;t<2;t++){
    if (t >= n) break;
    cplx v = val[t];
    if (l == 1)      val[t] = { v.im, -v.re};   // *(-i)
    else if (l == 2) val[t] = {-v.re, -v.im};   // *(-1)
    else if (l == 3) val[t] = {-v.im,  v.re};   // *(+i)
  }
  return n;
}
__constant__ int cPL1[N_PATHS]  = {0,0,0,1,1,1,1,1,1,1,2,2,2,2,2,2,2,2,2};
__constant__ int cPL2[N_PATHS]  = {0,1,2,0,1,1,1,2,2,2,0,1,1,1,2,2,2,2,2};
__constant__ int cPL3[N_PATHS]  = {0,1,2,1,0,1,2,1,2,3,2,1,2,3,0,1,2,3,4};
__constant__ int cCGOFF[N_PATHS]= {0,1,10,35,44,53,80,125,170,245,350,375,420,495,600,625,700,825,1000};

__global__ void setup_cg_kernel(){
  __shared__ double Tre[CG_TOTAL];
  __shared__ double Tim[CG_TOTAL];
  const int t = threadIdx.x;
  for (int idx = t; idx < CG_TOTAL; idx += blockDim.x){
    int p = N_PATHS-1;
    for (int q=0; q<N_PATHS-1; q++){ if (idx < cCGOFF[q+1]) { p = q; break; } }
    int loc = idx - cCGOFF[p];
    int l1 = cPL1[p], l2 = cPL2[p], l3 = cPL3[p];
    int D2 = 2*l2+1, D3 = 2*l3+1;
    int a = loc/(D2*D3); int rem = loc - a*(D2*D3); int b = rem/D3; int c = rem - b*D3;
    int c1[2], c2[2], c3[2]; cplx v1[2], v2[2], v3[2];
    int n1 = q_row(l1, a, c1, v1);
    int n2 = q_row(l2, b, c2, v2);
    int n3 = q_row(l3, c, c3, v3);
    cplx acc = {0.0, 0.0};
    for (int t1=0; t1<n1; t1++){
      for (int t2=0; t2<n2; t2++){
        int m1 = c1[t1]-l1, m2 = c2[t2]-l2;
        int kk = l3 + m1 + m2;
        if (kk < 0 || kk > 2*l3) continue;
        double cgv = su2_cg(l1,l2,l3,m1,m2);
        if (cgv == 0.0) continue;
        for (int t3=0; t3<n3; t3++){
          if (c3[t3] != kk) continue;
          cplx v3c = {v3[t3].re, -v3[t3].im};
          cplx prod = cmul(cmul(v1[t1], v2[t2]), v3c);
          acc.re += prod.re*cgv; acc.im += prod.im*cgv;
        }
      }
    }
    Tre[idx] = acc.re; Tim[idx] = acc.im;
  }
  __syncthreads();
  if (t < N_PATHS){
    int p = t, l3 = cPL3[p];
    int sz = (2*cPL1[p]+1)*(2*cPL2[p]+1)*(2*l3+1);
    int off = cCGOFF[p];
    double sre=0.0, sim=0.0;
    for (int e=0; e<sz; e++){ sre += fabs(Tre[off+e]); sim += fabs(Tim[off+e]); }
    bool useRe = (sre >= sim);
    double norm = 1.0/sqrt((double)(2*l3+1));
    for (int e=0; e<sz; e++){
      double v = useRe ? Tre[off+e] : Tim[off+e];
      g_cg[off+e] = (float)(v*norm);
    }
  }
}

// ---------------- W -> fragment-ordered bf16 (scale folded) ----------------
__global__ void prep_w_kernel(const float* __restrict__ W0, const float* __restrict__ W1,
                              const float* __restrict__ W2, const float* __restrict__ W3,
                              const float* __restrict__ W4, unsigned short* __restrict__ wout){
  int el = blockIdx.x*256 + threadIdx.x;
  if (el >= N_FRAGS*512) return;
  int frag = el>>9, r = el&511, lam = r>>3, j = r&7;
  int l  = (frag<12)?0 : (frag<36)?1 : (frag<60)?2 : (frag<66)?3 : 4;
  int fb = (l==0)?0 : (l==1)?12 : (l==2)?36 : (l==3)?60 : 66;
  int Ks = (l==0)?3 : (l==1)?6 : (l==2)?6 : (l==3)?3 : 1;
  int U  = (l==0)?96 : (l==1)?192 : (l==2)?192 : (l==3)?96 : 32;
  int rel = frag - fb, nt = rel/Ks, tt = rel - nt*Ks;
  int o = nt*16 + (lam&15);
  int u = tt*32 + (lam>>4)*8 + j;
  const float* W = (l==0)?W0 : (l==1)?W1 : (l==2)?W2 : (l==3)?W3 : W4;
  float scale = (l==0||l==3) ? 0.10206207261596575f
              : (l==4)       ? 0.17677669529663687f
                             : 0.07216878364870323f;
  wout[el] = f2bf(W[o*U + u] * scale);
}

// ---------------- main kernel ----------------
// One wave owns 16 samples end-to-end. A-frag (m89-validated layout):
// lane(s=lane&15, g=lane>>4), element j -> TP(sample s, mul g*8+j), K-dim=32 muls.
template<int L, int TT>
struct Slot {
  static constexpr int P  = kSP[L][TT];
  static constexpr int L1 = kPL1[P], L2_ = kPL2[P];
  static constexpr int D1 = 2*L1+1, D2 = 2*L2_+1;
  static constexpr int O1 = kIOFF[L1], O2 = kIOFF[L2_];
  static __device__ __forceinline__ void build(u32x4 (*af)[kKS[L]], const float* xa,
                                               const float* xb, int jp){
    constexpr int K = 2*L+1;
    float a0[K], a1[K];
    #pragma unroll
    for (int k=0;k<K;++k){ a0[k]=0.f; a1[k]=0.f; }
    #pragma unroll
    for (int i=0;i<D1;++i){
      #pragma unroll
      for (int jj=0;jj<D2;++jj){
        float p0 = xa[O1+i] * xb[O2+jj];
        float p1 = xa[9+O1+i] * xb[9+O2+jj];
        #pragma unroll
        for (int k=0;k<K;++k){
          if (nzp(L1, L2_, L, i, jj, k)){           // folds at compile time
            float w = g_cg[kCGOFF[P] + (i*D2+jj)*K + k];
            a0[k] = __builtin_fmaf(w, p0, a0[k]);
            a1[k] = __builtin_fmaf(w, p1, a1[k]);
          }
        }
      }
    }
    #pragma unroll
    for (int k=0;k<K;++k){
      unsigned pk;
      asm("v_cvt_pk_bf16_f32 %0, %1, %2" : "=v"(pk) : "v"(a0[k]), "v"(a1[k]));
      af[k][TT][jp] = pk;        // lo16 = j even, hi16 = j odd
    }
    if constexpr (TT+1 < kKS[L]) Slot<L, TT+1>::build(af, xa, xb, jp);
  }
};

template<int L>
__device__ __forceinline__ void do_group(const float* __restrict__ x1g,
                                         const float* __restrict__ x2g, bool act,
                                         const short* __restrict__ wfrag,
                                         float* slab, float* __restrict__ out,
                                         int nrowb, int N, int lane){
  constexpr int K = 2*L+1, Ks = kKS[L], Nt = kNT[L];
  const int s = lane&15, g = lane>>4;
  u32x4 af[K][Ks];

  // ---- build all A-frags for this group (j streamed in aligned pairs) ----
  #pragma unroll
  for (int jp=0; jp<4; ++jp){
    float xa[18], xb[18];
    #pragma unroll
    for (int e=0; e<9; ++e){
      float2 va = {0.f,0.f}, vb = {0.f,0.f};
      if (act){
        va = *reinterpret_cast<const float2*>(x1g + jp*18 + e*2);  // (jp*18+e*2)*4B: 8B-aligned
        vb = *reinterpret_cast<const float2*>(x2g + jp*18 + e*2);
      }
      xa[e*2] = va.x; xa[e*2+1] = va.y;
      xb[e*2] = vb.x; xb[e*2+1] = vb.y;
    }
    Slot<L,0>::build(af, xa, xb, jp);
  }

  // ---- MFMA + per-nt stage/flush (wave-synchronous, no barriers) ----
  const short* wf = wfrag + (size_t)kFB[L]*512 + (size_t)lane*8;
  #pragma unroll
  for (int nt=0; nt<Nt; ++nt){
    short8 bf[Ks];
    #pragma unroll
    for (int tt=0; tt<Ks; ++tt)
      bf[tt] = *reinterpret_cast<const short8*>(wf + (nt*Ks+tt)*512);
    f32x4 acc[K];
    #pragma unroll
    for (int k=0;k<K;++k) acc[k] = (f32x4){0.f,0.f,0.f,0.f};
    #pragma unroll
    for (int tt=0; tt<Ks; ++tt)
      #pragma unroll
      for (int k=0;k<K;++k)
        acc[k] = __builtin_amdgcn_mfma_f32_16x16x32_bf16(
                   __builtin_bit_cast(short8, af[k][tt]), bf[tt], acc[k], 0, 0, 0);
    // D-frag: row = sample g*4+r, col = o = nt*16+s  [m89 layout, r3/r4-validated]
    #pragma unroll
    for (int k=0;k<K;++k)
      #pragma unroll
      for (int r=0;r<4;++r)
        slab[(g*4+r)*SROW + s*K + k] = acc[k][r];
    // flush this nt: 16 samples x 16 o x K floats, full-64B-line float4 stores
    const int rr = lane>>2, q4 = lane&3;
    const float* sp = slab + rr*SROW;
    const bool on = (nrowb + rr) < N;
    float* op = out + (size_t)(nrowb+rr)*944 + kOB[L] + nt*16*K;
    #pragma unroll
    for (int c=0;c<K;++c){
      float4 v = *reinterpret_cast<const float4*>(sp + (c*4+q4)*4);
      if (on) *reinterpret_cast<float4*>(op + (c*4+q4)*4) = v;
    }
  }
}

__global__ __launch_bounds__(128, 2) void tp_main(
    const float* __restrict__ x1, const float* __restrict__ x2,
    const short* __restrict__ wfrag, float* __restrict__ out, int N)
{
  __shared__ __align__(16) float stage[2*16*SROW];
  const int t = threadIdx.x, w = t>>6, lane = t&63;
  const int nb = blockIdx.x*32 + w*16;
  const int s = lane&15, g = lane>>4;
  const int n = nb + s;
  const bool act = n < N;
  const size_t nbeg = (size_t)(act ? n : 0)*288 + g*72;
  const float* x1g = x1 + nbeg;
  const float* x2g = x2 + nbeg;
  float* slab = &stage[w*16*SROW];

  do_group<0>(x1g, x2g, act, wfrag, slab, out, nb, N, lane);
  do_group<1>(x1g, x2g, act, wfrag, slab, out, nb, N, lane);
  do_group<2>(x1g, x2g, act, wfrag, slab, out, nb, N, lane);
  do_group<3>(x1g, x2g, act, wfrag, slab, out, nb, N, lane);
  do_group<4>(x1g, x2g, act, wfrag, slab, out, nb, N, lane);
}

extern "C" void kernel_launch(void* const* d_in, const int* in_sizes, int n_in,
                              void* d_out, int out_size, void* d_ws, size_t ws_size,
                              hipStream_t stream)
{
  (void)n_in; (void)out_size; (void)ws_size;
  const float* x1 = (const float*)d_in[0];
  const float* x2 = (const float*)d_in[1];
  const float* W0 = (const float*)d_in[2];
  const float* W1 = (const float*)d_in[3];
  const float* W2 = (const float*)d_in[4];
  const float* W3 = (const float*)d_in[5];
  const float* W4 = (const float*)d_in[6];
  float* out = (float*)d_out;
  int N = in_sizes[0] / 288;

  setup_cg_kernel<<<dim3(1), dim3(256), 0, stream>>>();
  prep_w_kernel<<<dim3((N_FRAGS*512 + 255)/256), dim3(256), 0, stream>>>(
      W0, W1, W2, W3, W4, (unsigned short*)d_ws);
  int grid = (N + 31) / 32;
  tp_main<<<dim3(grid), dim3(128), 0, stream>>>(
      x1, x2, (const short*)d_ws, out, N);
}

// Round 6
// 257.713 us; speedup vs baseline: 18.7629x; 1.4897x over previous
//
#include <hip/hip_runtime.h>
#include <hip/hip_fp16.h>
#include <math.h>

typedef __attribute__((ext_vector_type(8))) short short8;
typedef __attribute__((ext_vector_type(4))) float f32x4;
typedef __attribute__((ext_vector_type(4))) unsigned u32x4;

#define N_PATHS 19
#define CG_TOTAL 1225
#define SROW 148            // slab row stride (floats)
#define HROW 290            // input LDS row stride in halves (145 dwords, odd -> 2-way banks)

// ---- compile-time path tables ----
constexpr int kPL1[N_PATHS]  = {0,0,0,1,1,1,1,1,1,1,2,2,2,2,2,2,2,2,2};
constexpr int kPL2[N_PATHS]  = {0,1,2,0,1,1,1,2,2,2,0,1,1,1,2,2,2,2,2};
constexpr int kCGOFF[N_PATHS]= {0,1,10,35,44,53,80,125,170,245,350,375,420,495,600,625,700,825,1000};
constexpr int kIOFF[3]  = {0,1,4};
constexpr int kSP[5][6] = {{0,4,14,0,0,0},{1,3,5,7,11,15},{2,6,8,10,12,16},{9,13,17,0,0,0},{18,0,0,0,0,0}};
constexpr int kKS[5] = {3,6,6,3,1};
constexpr int kNT[5] = {4,4,4,2,1};
constexpr int kOB[5] = {0,64,256,576,800};
constexpr int kFB[5] = {0,12,36,60,66};
#define N_FRAGS 67

__device__ float g_cg[CG_TOTAL];

// superset of the real-basis Wigner nonzero pattern: |m3| in {|m1|+|m2|, ||m1|-|m2||}.
// Extra entries multiply true zeros from g_cg: correctness-safe.
constexpr bool nzp(int l1, int l2, int l3, int i, int jj, int k){
  int m1 = i - l1, m2 = jj - l2, m3 = k - l3;
  int a1 = m1 < 0 ? -m1 : m1, a2 = m2 < 0 ? -m2 : m2, a3 = m3 < 0 ? -m3 : m3;
  int s = a1 + a2, d = a1 - a2; if (d < 0) d = -d;
  return a3 == s || a3 == d;
}

__device__ inline unsigned short f2bf(float v){  // RNE fp32->bf16
  unsigned u = __builtin_bit_cast(unsigned, v);
  unsigned r = u + 0x7FFFu + ((u>>16)&1u);
  return (unsigned short)(r>>16);
}

// ---------------- CG setup (every launch; deterministic) ----------------
struct cplx { double re, im; };
__device__ inline cplx cmul(cplx a, cplx b){ return {a.re*b.re - a.im*b.im, a.re*b.im + a.im*b.re}; }
__device__ inline double dfact(int n){
  const double f[10] = {1.,1.,2.,6.,24.,120.,720.,5040.,40320.,362880.};
  return f[n];
}
__device__ double su2_cg(int j1,int j2,int j3,int m1,int m2){
  int m3 = m1+m2;
  if (j3 < abs(j1-j2) || j3 > j1+j2 || abs(m3) > j3) return 0.0;
  double pref = (2.0*j3+1.0)*dfact(j3+j1-j2)*dfact(j3-j1+j2)*dfact(j1+j2-j3)/dfact(j1+j2+j3+1);
  pref = sqrt(pref);
  pref *= sqrt(dfact(j3+m3)*dfact(j3-m3)*dfact(j1-m1)*dfact(j1+m1)*dfact(j2-m2)*dfact(j2+m2));
  double s = 0.0;
  for (int k=0; k<=j1+j2-j3; ++k){
    int a1=j1+j2-j3-k, a2=j1-m1-k, a3=j2+m2-k, a4=j3-j2+m1+k, a5=j3-j1-m2+k;
    if (a1<0||a2<0||a3<0||a4<0||a5<0) continue;
    double d = dfact(k)*dfact(a1)*dfact(a2)*dfact(a3)*dfact(a4)*dfact(a5);
    s += ((k&1)? -1.0:1.0)/d;
  }
  return pref*s;
}
__device__ int q_row(int l, int r, int* col, cplx* val){
  const double rt = 0.70710678118654752440;
  int m = r - l; int n;
  if (m < 0){ col[0]=l-m; val[0]={rt,0.0}; col[1]=l+m; val[1]={0.0,-rt}; n=2; }
  else if (m == 0){ col[0]=l; val[0]={1.0,0.0}; n=1; }
  else { double s=(m&1)?-1.0:1.0; col[0]=l+m; val[0]={s*rt,0.0}; col[1]=l-m; val[1]={0.0,s*rt}; n=2; }
  #pragma unroll
  for (int t=0;t<2;t++){
    if (t >= n) break;
    cplx v = val[t];
    if (l == 1)      val[t] = { v.im, -v.re};   // *(-i)
    else if (l == 2) val[t] = {-v.re, -v.im};   // *(-1)
    else if (l == 3) val[t] = {-v.im,  v.re};   // *(+i)
  }
  return n;
}
__constant__ int cPL1[N_PATHS]  = {0,0,0,1,1,1,1,1,1,1,2,2,2,2,2,2,2,2,2};
__constant__ int cPL2[N_PATHS]  = {0,1,2,0,1,1,1,2,2,2,0,1,1,1,2,2,2,2,2};
__constant__ int cPL3[N_PATHS]  = {0,1,2,1,0,1,2,1,2,3,2,1,2,3,0,1,2,3,4};
__constant__ int cCGOFF[N_PATHS]= {0,1,10,35,44,53,80,125,170,245,350,375,420,495,600,625,700,825,1000};

__global__ void setup_cg_kernel(){
  __shared__ double Tre[CG_TOTAL];
  __shared__ double Tim[CG_TOTAL];
  const int t = threadIdx.x;
  for (int idx = t; idx < CG_TOTAL; idx += blockDim.x){
    int p = N_PATHS-1;
    for (int q=0; q<N_PATHS-1; q++){ if (idx < cCGOFF[q+1]) { p = q; break; } }
    int loc = idx - cCGOFF[p];
    int l1 = cPL1[p], l2 = cPL2[p], l3 = cPL3[p];
    int D2 = 2*l2+1, D3 = 2*l3+1;
    int a = loc/(D2*D3); int rem = loc - a*(D2*D3); int b = rem/D3; int c = rem - b*D3;
    int c1[2], c2[2], c3[2]; cplx v1[2], v2[2], v3[2];
    int n1 = q_row(l1, a, c1, v1);
    int n2 = q_row(l2, b, c2, v2);
    int n3 = q_row(l3, c, c3, v3);
    cplx acc = {0.0, 0.0};
    for (int t1=0; t1<n1; t1++){
      for (int t2=0; t2<n2; t2++){
        int m1 = c1[t1]-l1, m2 = c2[t2]-l2;
        int kk = l3 + m1 + m2;
        if (kk < 0 || kk > 2*l3) continue;
        double cgv = su2_cg(l1,l2,l3,m1,m2);
        if (cgv == 0.0) continue;
        for (int t3=0; t3<n3; t3++){
          if (c3[t3] != kk) continue;
          cplx v3c = {v3[t3].re, -v3[t3].im};
          cplx prod = cmul(cmul(v1[t1], v2[t2]), v3c);
          acc.re += prod.re*cgv; acc.im += prod.im*cgv;
        }
      }
    }
    Tre[idx] = acc.re; Tim[idx] = acc.im;
  }
  __syncthreads();
  if (t < N_PATHS){
    int p = t, l3 = cPL3[p];
    int sz = (2*cPL1[p]+1)*(2*cPL2[p]+1)*(2*l3+1);
    int off = cCGOFF[p];
    double sre=0.0, sim=0.0;
    for (int e=0; e<sz; e++){ sre += fabs(Tre[off+e]); sim += fabs(Tim[off+e]); }
    bool useRe = (sre >= sim);
    double norm = 1.0/sqrt((double)(2*l3+1));
    for (int e=0; e<sz; e++){
      double v = useRe ? Tre[off+e] : Tim[off+e];
      g_cg[off+e] = (float)(v*norm);
    }
  }
}

// ---------------- W -> fragment-ordered bf16 (scale folded) ----------------
__global__ void prep_w_kernel(const float* __restrict__ W0, const float* __restrict__ W1,
                              const float* __restrict__ W2, const float* __restrict__ W3,
                              const float* __restrict__ W4, unsigned short* __restrict__ wout){
  int el = blockIdx.x*256 + threadIdx.x;
  if (el >= N_FRAGS*512) return;
  int frag = el>>9, r = el&511, lam = r>>3, j = r&7;
  int l  = (frag<12)?0 : (frag<36)?1 : (frag<60)?2 : (frag<66)?3 : 4;
  int fb = (l==0)?0 : (l==1)?12 : (l==2)?36 : (l==3)?60 : 66;
  int Ks = (l==0)?3 : (l==1)?6 : (l==2)?6 : (l==3)?3 : 1;
  int U  = (l==0)?96 : (l==1)?192 : (l==2)?192 : (l==3)?96 : 32;
  int rel = frag - fb, nt = rel/Ks, tt = rel - nt*Ks;
  int o = nt*16 + (lam&15);
  int u = tt*32 + (lam>>4)*8 + j;
  const float* W = (l==0)?W0 : (l==1)?W1 : (l==2)?W2 : (l==3)?W3 : W4;
  float scale = (l==0||l==3) ? 0.10206207261596575f
              : (l==4)       ? 0.17677669529663687f
                             : 0.07216878364870323f;
  wout[el] = f2bf(W[o*U + u] * scale);
}

// ---------------- main kernel ----------------
// Block = 128 thr = 2 waves, 16 samples. Inputs staged once to LDS (fp16).
// wave0: groups {0,1,3} (126 MFMA), wave1: {2,4} (129 MFMA).
// A-frag (m89-validated): lane(s=lane&15,g=lane>>4), elem j -> TP(sample s, mul g*8+j).
template<int L, int TT>
struct Slot {
  static constexpr int P  = kSP[L][TT];
  static constexpr int L1 = kPL1[P], L2_ = kPL2[P];
  static constexpr int D1 = 2*L1+1, D2 = 2*L2_+1;
  static constexpr int O1 = kIOFF[L1], O2 = kIOFF[L2_];
  static __device__ __forceinline__ void build(u32x4 (*af)[kKS[L]], const float* xa,
                                               const float* xb, int jp){
    constexpr int K = 2*L+1;
    float a0[K], a1[K];
    #pragma unroll
    for (int k=0;k<K;++k){ a0[k]=0.f; a1[k]=0.f; }
    #pragma unroll
    for (int i=0;i<D1;++i){
      #pragma unroll
      for (int jj=0;jj<D2;++jj){
        float p0 = xa[O1+i] * xb[O2+jj];
        float p1 = xa[9+O1+i] * xb[9+O2+jj];
        #pragma unroll
        for (int k=0;k<K;++k){
          if (nzp(L1, L2_, L, i, jj, k)){           // folds at compile time
            float w = g_cg[kCGOFF[P] + (i*D2+jj)*K + k];
            a0[k] = __builtin_fmaf(w, p0, a0[k]);
            a1[k] = __builtin_fmaf(w, p1, a1[k]);
          }
        }
      }
    }
    #pragma unroll
    for (int k=0;k<K;++k){
      unsigned pk;
      asm("v_cvt_pk_bf16_f32 %0, %1, %2" : "=v"(pk) : "v"(a0[k]), "v"(a1[k]));
      af[k][TT][jp] = pk;        // lo16 = j even, hi16 = j odd
    }
    if constexpr (TT+1 < kKS[L]) Slot<L, TT+1>::build(af, xa, xb, jp);
  }
};

template<int L>
__device__ __forceinline__ void do_group(const __half* __restrict__ i1p,
                                         const __half* __restrict__ i2p,
                                         const short* __restrict__ wfrag,
                                         float* slab, float* __restrict__ out,
                                         int nrowb, int N, int lane){
  constexpr int K = 2*L+1, Ks = kKS[L], Nt = kNT[L];
  const int s = lane&15, g = lane>>4;
  u32x4 af[K][Ks];

  // ---- build all A-frags for this group from LDS inputs ----
  #pragma unroll
  for (int jp=0; jp<4; ++jp){
    float xa[18], xb[18];
    #pragma unroll
    for (int e=0; e<9; ++e){
      __half2 va = *reinterpret_cast<const __half2*>(i1p + jp*18 + e*2);
      __half2 vb = *reinterpret_cast<const __half2*>(i2p + jp*18 + e*2);
      xa[e*2] = __half2float(va.x); xa[e*2+1] = __half2float(va.y);
      xb[e*2] = __half2float(vb.x); xb[e*2+1] = __half2float(vb.y);
    }
    Slot<L,0>::build(af, xa, xb, jp);
  }

  // ---- MFMA + per-nt stage/flush (wave-synchronous, no barriers) ----
  const short* wf = wfrag + (size_t)kFB[L]*512 + (size_t)lane*8;
  #pragma unroll
  for (int nt=0; nt<Nt; ++nt){
    short8 bf[Ks];
    #pragma unroll
    for (int tt=0; tt<Ks; ++tt)
      bf[tt] = *reinterpret_cast<const short8*>(wf + (nt*Ks+tt)*512);
    f32x4 acc[K];
    #pragma unroll
    for (int k=0;k<K;++k) acc[k] = (f32x4){0.f,0.f,0.f,0.f};
    #pragma unroll
    for (int tt=0; tt<Ks; ++tt)
      #pragma unroll
      for (int k=0;k<K;++k)
        acc[k] = __builtin_amdgcn_mfma_f32_16x16x32_bf16(
                   __builtin_bit_cast(short8, af[k][tt]), bf[tt], acc[k], 0, 0, 0);
    // D-frag: row = sample g*4+r, col = o = nt*16+s  [m89 layout]
    #pragma unroll
    for (int k=0;k<K;++k)
      #pragma unroll
      for (int r=0;r<4;++r)
        slab[(g*4+r)*SROW + s*K + k] = acc[k][r];
    // flush this nt: 16 samples x (16 o x K) floats, full-64B-line float4 stores
    const int rr = lane>>2, q4 = lane&3;
    const float* sp = slab + rr*SROW;
    const bool on = (nrowb + rr) < N;
    float* op = out + (size_t)(nrowb+rr)*944 + kOB[L] + nt*16*K;
    #pragma unroll
    for (int c=0;c<K;++c){
      float4 v = *reinterpret_cast<const float4*>(sp + (c*4+q4)*4);
      if (on) *reinterpret_cast<float4*>(op + (c*4+q4)*4) = v;
    }
  }
}

__global__ __launch_bounds__(128, 2) void tp_main(
    const float* __restrict__ x1, const float* __restrict__ x2,
    const short* __restrict__ wfrag, float* __restrict__ out, int N)
{
  __shared__ __align__(16) __half in1h[16*HROW];
  __shared__ __align__(16) __half in2h[16*HROW];
  __shared__ __align__(16) float stage[2*16*SROW];
  const int t = threadIdx.x, w = t>>6, lane = t&63;
  const int nb = blockIdx.x*16;

  // stage 16 samples as fp16 (float4 global -> half4 LDS)
  for (int idx = t; idx < 16*72; idx += 128){
    int row = idx/72, c4 = idx - row*72;
    int n = nb + row;
    float4 v1 = {0,0,0,0}, v2 = {0,0,0,0};
    if (n < N){
      v1 = reinterpret_cast<const float4*>(x1 + (size_t)n*288)[c4];
      v2 = reinterpret_cast<const float4*>(x2 + (size_t)n*288)[c4];
    }
    int b = row*HROW + c4*4;
    ushort4 u1, u2;
    u1.x = __half_as_ushort(__float2half_rn(v1.x)); u1.y = __half_as_ushort(__float2half_rn(v1.y));
    u1.z = __half_as_ushort(__float2half_rn(v1.z)); u1.w = __half_as_ushort(__float2half_rn(v1.w));
    u2.x = __half_as_ushort(__float2half_rn(v2.x)); u2.y = __half_as_ushort(__float2half_rn(v2.y));
    u2.z = __half_as_ushort(__float2half_rn(v2.z)); u2.w = __half_as_ushort(__float2half_rn(v2.w));
    *reinterpret_cast<ushort4*>(&in1h[b]) = u1;
    *reinterpret_cast<ushort4*>(&in2h[b]) = u2;
  }
  __syncthreads();

  const int s = lane&15, g = lane>>4;
  const __half* i1p = &in1h[s*HROW + g*72];
  const __half* i2p = &in2h[s*HROW + g*72];
  float* slab = &stage[w*16*SROW];

  if (w == 0){
    do_group<0>(i1p, i2p, wfrag, slab, out, nb, N, lane);
    do_group<1>(i1p, i2p, wfrag, slab, out, nb, N, lane);
    do_group<3>(i1p, i2p, wfrag, slab, out, nb, N, lane);
  } else {
    do_group<2>(i1p, i2p, wfrag, slab, out, nb, N, lane);
    do_group<4>(i1p, i2p, wfrag, slab, out, nb, N, lane);
  }
}

extern "C" void kernel_launch(void* const* d_in, const int* in_sizes, int n_in,
                              void* d_out, int out_size, void* d_ws, size_t ws_size,
                              hipStream_t stream)
{
  (void)n_in; (void)out_size; (void)ws_size;
  const float* x1 = (const float*)d_in[0];
  const float* x2 = (const float*)d_in[1];
  const float* W0 = (const float*)d_in[2];
  const float* W1 = (const float*)d_in[3];
  const float* W2 = (const float*)d_in[4];
  const float* W3 = (const float*)d_in[5];
  const float* W4 = (const float*)d_in[6];
  float* out = (float*)d_out;
  int N = in_sizes[0] / 288;

  setup_cg_kernel<<<dim3(1), dim3(256), 0, stream>>>();
  prep_w_kernel<<<dim3((N_FRAGS*512 + 255)/256), dim3(256), 0, stream>>>(
      W0, W1, W2, W3, W4, (unsigned short*)d_ws);
  int grid = (N + 15) / 16;
  tp_main<<<dim3(grid), dim3(128), 0, stream>>>(
      x1, x2, (const short*)d_ws, out, N);
}

// Round 7
// 110.403 us; speedup vs baseline: 43.7981x; 2.3343x over previous
//
#include <hip/hip_runtime.h>
#include <hip/hip_fp16.h>
#include <array>

typedef __attribute__((ext_vector_type(8))) short short8;
typedef __attribute__((ext_vector_type(4))) float f32x4;
typedef __attribute__((ext_vector_type(4))) unsigned u32x4;

#define N_PATHS 19
#define SROW 148            // slab row stride (floats)
#define HROW 290            // input LDS row stride in halves

// ---- compile-time path tables ----
constexpr int kPL1[N_PATHS]  = {0,0,0,1,1,1,1,1,1,1,2,2,2,2,2,2,2,2,2};
constexpr int kPL2[N_PATHS]  = {0,1,2,0,1,1,1,2,2,2,0,1,1,1,2,2,2,2,2};
constexpr int kPL3[N_PATHS]  = {0,1,2,1,0,1,2,1,2,3,2,1,2,3,0,1,2,3,4};
constexpr int kIOFF[3]  = {0,1,4};
constexpr int kSP[5][6] = {{0,4,14,0,0,0},{1,3,5,7,11,15},{2,6,8,10,12,16},{9,13,17,0,0,0},{18,0,0,0,0,0}};
constexpr int kKS[5] = {3,6,6,3,1};
constexpr int kNT[5] = {4,4,4,2,1};
constexpr int kOB[5] = {0,64,256,576,800};
constexpr int kFB[5] = {0,12,36,60,66};
#define N_FRAGS 67

// ================= constexpr Wigner tables (same math as r2-validated device path) ==========
struct ccplx { double re, im; };
constexpr ccplx cmulc(ccplx a, ccplx b){ return {a.re*b.re - a.im*b.im, a.re*b.im + a.im*b.re}; }
constexpr double cfact(int n){ double f = 1.0; for (int i = 2; i <= n; ++i) f *= i; return f; }
constexpr double csqrt(double x){
  if (x <= 0.0) return 0.0;
  double g = x > 1.0 ? x : 1.0;
  for (int i = 0; i < 64; ++i) g = 0.5*(g + x/g);
  return g;
}
constexpr double c_su2cg(int j1,int j2,int j3,int m1,int m2){
  int m3 = m1+m2;
  int am3 = m3 < 0 ? -m3 : m3;
  int dj = j1-j2 < 0 ? j2-j1 : j1-j2;
  if (j3 < dj || j3 > j1+j2 || am3 > j3) return 0.0;
  double pref = (2.0*j3+1.0)*cfact(j3+j1-j2)*cfact(j3-j1+j2)*cfact(j1+j2-j3)/cfact(j1+j2+j3+1);
  pref = csqrt(pref);
  pref *= csqrt(cfact(j3+m3)*cfact(j3-m3)*cfact(j1-m1)*cfact(j1+m1)*cfact(j2-m2)*cfact(j2+m2));
  double s = 0.0;
  for (int k = 0; k <= j1+j2-j3; ++k){
    int a1=j1+j2-j3-k, a2=j1-m1-k, a3=j2+m2-k, a4=j3-j2+m1+k, a5=j3-j1-m2+k;
    if (a1<0||a2<0||a3<0||a4<0||a5<0) continue;
    double d = cfact(k)*cfact(a1)*cfact(a2)*cfact(a3)*cfact(a4)*cfact(a5);
    s += ((k&1) ? -1.0 : 1.0)/d;
  }
  return pref*s;
}
// q(l)[r][c] incl. (-i)^l rotation (l=1:-i, l=2:-1, l=3:+i)  [r1-bug-fixed, r2-validated]
constexpr ccplx qel(int l, int r, int c){
  const double rt = 0.70710678118654752440;
  int m = r - l;
  ccplx v{0.0, 0.0};
  if (m < 0){
    if (c == l - m) v = {rt, 0.0};
    else if (c == l + m) v = {0.0, -rt};
  } else if (m == 0){
    if (c == l) v = {1.0, 0.0};
  } else {
    double s = (m & 1) ? -1.0 : 1.0;
    if (c == l + m) v = {s*rt, 0.0};
    else if (c == l - m) v = {0.0, s*rt};
  }
  int ph = l & 3;
  if (ph == 1) return { v.im, -v.re};
  if (ph == 2) return {-v.re, -v.im};
  if (ph == 3) return {-v.im,  v.re};
  return v;
}
template<int P>
constexpr auto make_cg(){
  constexpr int l1 = kPL1[P], l2 = kPL2[P], l3 = kPL3[P];
  constexpr int D1 = 2*l1+1, D2v = 2*l2+1, D3 = 2*l3+1;
  double su[D1][D2v] = {};
  for (int i = 0; i < D1; ++i)
    for (int j = 0; j < D2v; ++j)
      su[i][j] = c_su2cg(l1, l2, l3, i-l1, j-l2);
  std::array<double, (size_t)D1*D2v*D3> re{}, im{};
  double sre = 0.0, sim = 0.0;
  for (int a = 0; a < D1; ++a)
    for (int b = 0; b < D2v; ++b)
      for (int c = 0; c < D3; ++c){
        ccplx acc{0.0, 0.0};
        for (int i = 0; i < D1; ++i)
          for (int j = 0; j < D2v; ++j){
            int kk = l3 + (i-l1) + (j-l2);
            if (kk < 0 || kk >= D3) continue;
            double cgv = su[i][j];
            if (cgv == 0.0) continue;
            ccplx q3 = qel(l3, c, kk);
            ccplx pr = cmulc(cmulc(qel(l1,a,i), qel(l2,b,j)), ccplx{q3.re, -q3.im});
            acc.re += pr.re*cgv; acc.im += pr.im*cgv;
          }
        size_t e = ((size_t)a*D2v + b)*D3 + c;
        re[e] = acc.re; im[e] = acc.im;
        sre += acc.re < 0 ? -acc.re : acc.re;
        sim += acc.im < 0 ? -acc.im : acc.im;
      }
  std::array<float, (size_t)D1*D2v*D3> out{};
  const bool useRe = (sre >= sim);
  const double norm = 1.0/csqrt((double)D3);
  for (size_t e = 0; e < out.size(); ++e){
    double v = (useRe ? re[e] : im[e])*norm;
    if (v < 1e-10 && v > -1e-10) v = 0.0;
    out[e] = (float)v;
  }
  return out;
}
template<int P> struct CGTab { static constexpr auto tab = make_cg<P>(); };
template<int P, int K> constexpr bool row_any(int E){
  for (int k = 0; k < K; ++k) if (CGTab<P>::tab[(size_t)E*K + k] != 0.0f) return true;
  return false;
}

__device__ inline unsigned short f2bf(float v){  // RNE fp32->bf16
  unsigned u = __builtin_bit_cast(unsigned, v);
  unsigned r = u + 0x7FFFu + ((u>>16)&1u);
  return (unsigned short)(r>>16);
}

// ---------------- W -> fragment-ordered bf16 (scale folded) ----------------
__global__ void prep_w_kernel(const float* __restrict__ W0, const float* __restrict__ W1,
                              const float* __restrict__ W2, const float* __restrict__ W3,
                              const float* __restrict__ W4, unsigned short* __restrict__ wout){
  int el = blockIdx.x*256 + threadIdx.x;
  if (el >= N_FRAGS*512) return;
  int frag = el>>9, r = el&511, lam = r>>3, j = r&7;
  int l  = (frag<12)?0 : (frag<36)?1 : (frag<60)?2 : (frag<66)?3 : 4;
  int fb = (l==0)?0 : (l==1)?12 : (l==2)?36 : (l==3)?60 : 66;
  int Ks = (l==0)?3 : (l==1)?6 : (l==2)?6 : (l==3)?3 : 1;
  int U  = (l==0)?96 : (l==1)?192 : (l==2)?192 : (l==3)?96 : 32;
  int rel = frag - fb, nt = rel/Ks, tt = rel - nt*Ks;
  int o = nt*16 + (lam&15);
  int u = tt*32 + (lam>>4)*8 + j;
  const float* W = (l==0)?W0 : (l==1)?W1 : (l==2)?W2 : (l==3)?W3 : W4;
  float scale = (l==0||l==3) ? 0.10206207261596575f
              : (l==4)       ? 0.17677669529663687f
                             : 0.07216878364870323f;
  wout[el] = f2bf(W[o*U + u] * scale);
}

// ---------------- main kernel ----------------
// Block = 128 thr = 2 waves, 16 samples; wave0: groups {0,1,3}, wave1: {2,4}.
// A-frag (m89-validated): lane(s=lane&15,g=lane>>4), elem j -> TP(sample s, mul g*8+j).
// CG coefficients are instruction immediates via constexpr tables.

template<int P, int K, int E, int KK>
struct CKk {
  static __device__ __forceinline__ void run(float (&a0)[K], float (&a1)[K], float p0, float p1){
    constexpr float w = CGTab<P>::tab[(size_t)E*K + KK];
    if constexpr (w != 0.0f){
      a0[KK] = __builtin_fmaf(w, p0, a0[KK]);
      a1[KK] = __builtin_fmaf(w, p1, a1[KK]);
    }
    if constexpr (KK+1 < K) CKk<P,K,E,KK+1>::run(a0, a1, p0, p1);
  }
};

template<int P, int K, int D2v, int O1, int O2, int E, int NE>
struct CElem {
  static __device__ __forceinline__ void run(float (&a0)[K], float (&a1)[K],
                                             const float* xa, const float* xb){
    if constexpr (row_any<P,K>(E)){
      constexpr int i = E / D2v, jj = E - i*D2v;
      float p0 = xa[O1+i] * xb[O2+jj];
      float p1 = xa[9+O1+i] * xb[9+O2+jj];
      CKk<P,K,E,0>::run(a0, a1, p0, p1);
    }
    if constexpr (E+1 < NE) CElem<P,K,D2v,O1,O2,E+1,NE>::run(a0, a1, xa, xb);
  }
};

template<int L, int TT>
struct Slot {
  static constexpr int P  = kSP[L][TT];
  static constexpr int L1 = kPL1[P], L2_ = kPL2[P];
  static constexpr int D1 = 2*L1+1, D2v = 2*L2_+1;
  static constexpr int O1 = kIOFF[L1], O2 = kIOFF[L2_];
  static __device__ __forceinline__ void build(u32x4 (*af)[kKS[L]], const float* xa,
                                               const float* xb, int jp){
    constexpr int K = 2*L+1;
    float a0[K], a1[K];
    #pragma unroll
    for (int k=0;k<K;++k){ a0[k]=0.f; a1[k]=0.f; }
    CElem<P,K,D2v,O1,O2,0,D1*D2v>::run(a0, a1, xa, xb);
    #pragma unroll
    for (int k=0;k<K;++k){
      unsigned pk;
      asm("v_cvt_pk_bf16_f32 %0, %1, %2" : "=v"(pk) : "v"(a0[k]), "v"(a1[k]));
      af[k][TT][jp] = pk;        // lo16 = j even, hi16 = j odd
    }
    if constexpr (TT+1 < kKS[L]) Slot<L, TT+1>::build(af, xa, xb, jp);
  }
};

template<int L>
__device__ __forceinline__ void do_group(const __half* __restrict__ i1p,
                                         const __half* __restrict__ i2p,
                                         const short* __restrict__ wfrag,
                                         float* slab, float* __restrict__ out,
                                         int nrowb, int N, int lane){
  constexpr int K = 2*L+1, Ks = kKS[L], Nt = kNT[L];
  const int s = lane&15, g = lane>>4;
  u32x4 af[K][Ks];

  // ---- build all A-frags for this group from LDS inputs (CG = immediates) ----
  #pragma unroll
  for (int jp=0; jp<4; ++jp){
    float xa[18], xb[18];
    #pragma unroll
    for (int e=0; e<9; ++e){
      __half2 va = *reinterpret_cast<const __half2*>(i1p + jp*18 + e*2);
      __half2 vb = *reinterpret_cast<const __half2*>(i2p + jp*18 + e*2);
      xa[e*2] = __half2float(va.x); xa[e*2+1] = __half2float(va.y);
      xb[e*2] = __half2float(vb.x); xb[e*2+1] = __half2float(vb.y);
    }
    Slot<L,0>::build(af, xa, xb, jp);
  }

  // ---- MFMA + per-nt stage/flush; B-frags double-buffered ----
  const short* wf = wfrag + (size_t)kFB[L]*512 + (size_t)lane*8;
  short8 bfc[Ks], bfn[Ks];
  #pragma unroll
  for (int tt=0; tt<Ks; ++tt)
    bfc[tt] = *reinterpret_cast<const short8*>(wf + tt*512);
  #pragma unroll
  for (int nt=0; nt<Nt; ++nt){
    if (nt+1 < Nt){
      #pragma unroll
      for (int tt=0; tt<Ks; ++tt)
        bfn[tt] = *reinterpret_cast<const short8*>(wf + ((nt+1)*Ks+tt)*512);
    }
    f32x4 acc[K];
    #pragma unroll
    for (int k=0;k<K;++k) acc[k] = (f32x4){0.f,0.f,0.f,0.f};
    #pragma unroll
    for (int tt=0; tt<Ks; ++tt)
      #pragma unroll
      for (int k=0;k<K;++k)
        acc[k] = __builtin_amdgcn_mfma_f32_16x16x32_bf16(
                   __builtin_bit_cast(short8, af[k][tt]), bfc[tt], acc[k], 0, 0, 0);
    // D-frag: row = sample g*4+r, col = o = nt*16+s  [m89 layout]
    #pragma unroll
    for (int k=0;k<K;++k)
      #pragma unroll
      for (int r=0;r<4;++r)
        slab[(g*4+r)*SROW + s*K + k] = acc[k][r];
    // flush this nt: 16 samples x (16 o x K) floats, full-64B-line float4 stores
    const int rr = lane>>2, q4 = lane&3;
    const float* sp = slab + rr*SROW;
    const bool on = (nrowb + rr) < N;
    float* op = out + (size_t)(nrowb+rr)*944 + kOB[L] + nt*16*K;
    #pragma unroll
    for (int c=0;c<K;++c){
      float4 v = *reinterpret_cast<const float4*>(sp + (c*4+q4)*4);
      if (on) *reinterpret_cast<float4*>(op + (c*4+q4)*4) = v;
    }
    if (nt+1 < Nt){
      #pragma unroll
      for (int tt=0; tt<Ks; ++tt) bfc[tt] = bfn[tt];
    }
  }
}

__global__ __launch_bounds__(128, 2) void tp_main(
    const float* __restrict__ x1, const float* __restrict__ x2,
    const short* __restrict__ wfrag, float* __restrict__ out, int N)
{
  __shared__ __align__(16) __half in1h[16*HROW];
  __shared__ __align__(16) __half in2h[16*HROW];
  __shared__ __align__(16) float stage[2*16*SROW];
  const int t = threadIdx.x, w = t>>6, lane = t&63;
  const int nb = blockIdx.x*16;

  // stage 16 samples as fp16 (float4 global -> half4 LDS)
  for (int idx = t; idx < 16*72; idx += 128){
    int row = idx/72, c4 = idx - row*72;
    int n = nb + row;
    float4 v1 = {0,0,0,0}, v2 = {0,0,0,0};
    if (n < N){
      v1 = reinterpret_cast<const float4*>(x1 + (size_t)n*288)[c4];
      v2 = reinterpret_cast<const float4*>(x2 + (size_t)n*288)[c4];
    }
    int b = row*HROW + c4*4;
    ushort4 u1, u2;
    u1.x = __half_as_ushort(__float2half_rn(v1.x)); u1.y = __half_as_ushort(__float2half_rn(v1.y));
    u1.z = __half_as_ushort(__float2half_rn(v1.z)); u1.w = __half_as_ushort(__float2half_rn(v1.w));
    u2.x = __half_as_ushort(__float2half_rn(v2.x)); u2.y = __half_as_ushort(__float2half_rn(v2.y));
    u2.z = __half_as_ushort(__float2half_rn(v2.z)); u2.w = __half_as_ushort(__float2half_rn(v2.w));
    *reinterpret_cast<ushort4*>(&in1h[b]) = u1;
    *reinterpret_cast<ushort4*>(&in2h[b]) = u2;
  }
  __syncthreads();

  const int s = lane&15, g = lane>>4;
  const __half* i1p = &in1h[s*HROW + g*72];
  const __half* i2p = &in2h[s*HROW + g*72];
  float* slab = &stage[w*16*SROW];

  if (w == 0){
    do_group<0>(i1p, i2p, wfrag, slab, out, nb, N, lane);
    do_group<1>(i1p, i2p, wfrag, slab, out, nb, N, lane);
    do_group<3>(i1p, i2p, wfrag, slab, out, nb, N, lane);
  } else {
    do_group<2>(i1p, i2p, wfrag, slab, out, nb, N, lane);
    do_group<4>(i1p, i2p, wfrag, slab, out, nb, N, lane);
  }
}

extern "C" void kernel_launch(void* const* d_in, const int* in_sizes, int n_in,
                              void* d_out, int out_size, void* d_ws, size_t ws_size,
                              hipStream_t stream)
{
  (void)n_in; (void)out_size; (void)ws_size;
  const float* x1 = (const float*)d_in[0];
  const float* x2 = (const float*)d_in[1];
  const float* W0 = (const float*)d_in[2];
  const float* W1 = (const float*)d_in[3];
  const float* W2 = (const float*)d_in[4];
  const float* W3 = (const float*)d_in[5];
  const float* W4 = (const float*)d_in[6];
  float* out = (float*)d_out;
  int N = in_sizes[0] / 288;

  prep_w_kernel<<<dim3((N_FRAGS*512 + 255)/256), dim3(256), 0, stream>>>(
      W0, W1, W2, W3, W4, (unsigned short*)d_ws);
  int grid = (N + 15) / 16;
  tp_main<<<dim3(grid), dim3(128), 0, stream>>>(
      x1, x2, (const short*)d_ws, out, N);
}